// Round 13
// baseline (84.266 us; speedup 1.0000x reference)
//
#include <hip/hip_runtime.h>
#include <hip/hip_bf16.h>

#define DM 1024
#define HID 64
#define NSTEP 6
#define RSTEP (1.0f/6.0f)

using short8  = __attribute__((ext_vector_type(8))) short;
using short4v = __attribute__((ext_vector_type(4))) short;
using f32x4   = __attribute__((ext_vector_type(4))) float;

// workspace byte offsets
#define WS_W1P 0          // 1024x64 bf16 packed A-frags (131072 B)
#define WS_W2P 131072     // 64x1024 bf16 packed A-frags (131072 B)
#define WS_GP  262144     // 64x64 bf16 packed A-frags (8192 B)
#define WS_U   270336     // 64 f32  (u = b2 @ W1k)
#define WS_VST 270592     // 24x64 f32 affine stage consts (6144 B)
#define WS_HU  276736     // 64 f32  (h*u) (256 B)

// LDS per block (1 wave): H-buf + VST + HU = 8704 B
#define L_H   0           // H [16][72] bf16, pitch 144 (2304)
#define L_VST 2304        // VST staged (6144)
#define L_HU  8448        // h*u staged (256)
#define LDS_TOTAL 8704
#define HP 144

// Intra-wave LDS ordering only: the DS pipe services a wave's LDS ops in
// order; this stops the compiler migrating ds ops across phases. The
// whole kernel has ZERO s_barrier (one wave per block).
#define FENCE() asm volatile("s_waitcnt lgkmcnt(0)" ::: "memory")

__device__ __forceinline__ short f2bf(float f) {   // RNE via HW cvt
    __hip_bfloat16 h = __float2bfloat16(f);
    short s;
    __builtin_memcpy(&s, &h, 2);
    return s;
}
__device__ __forceinline__ float ftanh(float x) {
    x = fminf(fmaxf(x, -10.f), 10.f);
    float e = __expf(2.f * x);
    return __fdividef(e - 1.f, e + 1.f);
}

// ---------------- prep: pack weights + precompute stage tables ----------------
// A-frag layout for mfma_f32_16x16x32_bf16: lane l holds M-row (l&15),
// k = (l>>4)*8 + i (8 consecutive k). Packed so each lane loads one short8.
__global__ void k_prep(const float* __restrict__ W1, const float* __restrict__ W2,
                       const float* __restrict__ b1, const float* __restrict__ b2,
                       short* __restrict__ W1P, short* __restrict__ W2P,
                       short* __restrict__ GP, float* __restrict__ U,
                       float* __restrict__ VST, float* __restrict__ HU) {
    __shared__ float red[4][64];
    int b = blockIdx.x;
    int t = threadIdx.x;           // 256 threads
    int l = t & 63, q4 = t >> 6;
    if (b < 128) {                 // W1k (1024x64) -> W1P[kk<32][c<4][l][8]
        if (t < 64) {
            int kk = b >> 2, c = b & 3;
            int col = c * 16 + (l & 15);
            int kb = kk * 32 + ((l >> 4) << 3);
            short8 v;
            #pragma unroll
            for (int i = 0; i < 8; ++i) v[i] = f2bf(W1[(kb + i) * HID + col]);
            *(short8*)(W1P + (((kk * 4 + c) * 64) + l) * 8) = v;
        }
    } else if (b < 256) {          // W2 (64x1024) -> W2P[kk2<2][ct<64][l][8]
        if (t < 64) {
            int bb = b - 128;
            int kk2 = bb >> 6, ct = bb & 63;
            int col = ct * 16 + (l & 15);
            int kb = kk2 * 32 + ((l >> 4) << 3);
            short8 v;
            #pragma unroll
            for (int i = 0; i < 8; ++i) v[i] = f2bf(W2[(kb + i) * DM + col]);
            *(short8*)(W2P + (((kk2 * 64 + ct) * 64) + l) * 8) = v;
        }
    } else if (b < 320) {          // G[j][i] = sum_d W2[j][d]*W1[d][i]; j = b-256
        int j = b - 256;
        float acc = 0.f;
        #pragma unroll 8
        for (int d = q4 * 256; d < q4 * 256 + 256; ++d)
            acc += W2[j * DM + d] * W1[d * HID + l];
        red[q4][l] = acc;
        __syncthreads();
        if (t < 64) {
            float a = red[0][l] + red[1][l] + red[2][l] + red[3][l];
            int kk = j >> 5, lk = (j >> 3) & 3, ii = j & 7, c = l >> 4, lo = l & 15;
            GP[(((kk * 4 + c) * 64) + lk * 16 + lo) * 8 + ii] = f2bf(a);
        }
    } else {                       // u = b2@W1k, then HU = h*u and the
        float acc = 0.f;           // VST[s][e] = c_e*u + t_e*w1t + b1 table
        #pragma unroll 8
        for (int d = q4 * 256; d < q4 * 256 + 256; ++d)
            acc += b2[d] * W1[d * HID + l];
        red[q4][l] = acc;
        __syncthreads();
        if (t < 64) {
            float uu = red[0][l] + red[1][l] + red[2][l] + red[3][l];
            U[l] = uu;
            HU[l] = RSTEP * uu;
            float b1l = b1[l];
            float wtl = W1[DM * HID + l];        // time row of W1
            #pragma unroll
            for (int s6 = 0; s6 < 6; ++s6) {
                float ts = RSTEP * (float)s6;
                float tm = ts + 0.5f * RSTEP;
                float vmid = b1l + tm * wtl + 0.5f * RSTEP * uu;
                VST[(s6 * 4 + 0) * 64 + l] = b1l + ts * wtl;
                VST[(s6 * 4 + 1) * 64 + l] = vmid;
                VST[(s6 * 4 + 2) * 64 + l] = vmid;
                VST[(s6 * 4 + 3) * 64 + l] = b1l + (ts + RSTEP) * wtl + RSTEP * uu;
            }
        }
    }
}

// ---------------- fused RK4 neural-ODE kernel (wave-local, 0 barriers) --------
// One WAVE owns one 16-row group end-to-end. Algebra (R7+R12, verified):
//   sz' = sz + Hb@G + h*u  (incremental, GEMM1 once in prologue)
//   z_T = x + S@W2 + b2,   S = sum_s (h/6)*Hsum_s  (f32 accum, one epilogue GEMM)
// Per step: 4 stage evals (each: read H B-frags, 8 MFMA H@G, 16-elem tanh,
// write H) + 8-MFMA sz update. All exchange through the wave's PRIVATE
// LDS H-buffer, single-buffered: intra-wave DS ops are serviced in order,
// so read-old-then-write-new is safe (R5/R11-proven); FENCE stops compiler
// reordering. ZERO s_barrier in the kernel; 1024 independent wave-chains
// (= total problem parallelism), 1/SIMD, no convoy (R12's 24-barrier cost)
// and no redundancy (R11's 4x VALU mistake).
// T_e = sz + c_e*dd + VST[s][e] with VST precomputed by k_prep (saves the
// u4/b14/w1t4 per-c register sets and ~30 VALU/step).
// G frags pinned in 32 VGPRs. MFMA: A = packed weights (M = out-col),
// B = z/H rows (N = row). D: m=(lane>>4)*4+reg (col), n=lane&15 (row).
// ALLOCATION: amdgpu_waves_per_eu(2,4) — only attr honored at VGPR<=128
// with no spill (12-round ledger). Live-set ~105 regs.
__global__ __launch_bounds__(64) __attribute__((amdgpu_waves_per_eu(2, 4)))
void k_ode(
        const float* __restrict__ X, const float* __restrict__ b2,
        const short* __restrict__ W1P, const short* __restrict__ W2P,
        const short* __restrict__ GP, const float* __restrict__ VST,
        const float* __restrict__ HU, float* __restrict__ OUT) {
    extern __shared__ char smem[];
    const int lane = threadIdx.x & 63;
    const int hq = lane >> 4;
    const int l15 = lane & 15;
    const size_t row0 = (size_t)blockIdx.x * 16;
    const float* xrow = X + (row0 + l15) * DM;

    // stage VST + HU into LDS (reads are same-wave, in-order DS pipe)
    #pragma unroll
    for (int i = 0; i < 6; ++i)
        *(f32x4*)(smem + L_VST + i * 1024 + lane * 16) =
            *(const f32x4*)(VST + i * 256 + lane * 4);
    if (lane < 16)
        *(f32x4*)(smem + L_HU + lane * 16) = *(const f32x4*)(HU + lane * 4);

    // pinned G A-frags: gfr[kslice][c-tile]
    short8 gfr[2][4];
    #pragma unroll
    for (int k2 = 0; k2 < 2; ++k2)
        #pragma unroll
        for (int c = 0; c < 4; ++c)
            gfr[k2][c] = *(const short8*)(GP + ((k2 * 4 + c) * 64 + lane) * 8);

    // ---- prologue GEMM1 (once): sz[c] = (x @ W1k) for all 4 c-tiles ----
    f32x4 sz[4] = {(f32x4){0.f,0.f,0.f,0.f}, (f32x4){0.f,0.f,0.f,0.f},
                   (f32x4){0.f,0.f,0.f,0.f}, (f32x4){0.f,0.f,0.f,0.f}};
    {
        const short8* wp = (const short8*)W1P;
        #pragma unroll 4
        for (int kk = 0; kk < 32; ++kk) {
            const float* xp = xrow + (kk << 5) + (hq << 3);
            f32x4 lo = *(const f32x4*)(xp);
            f32x4 hi = *(const f32x4*)(xp + 4);
            short8 zf;
            #pragma unroll
            for (int j = 0; j < 4; ++j) { zf[j] = f2bf(lo[j]); zf[4 + j] = f2bf(hi[j]); }
            #pragma unroll
            for (int c = 0; c < 4; ++c)
                sz[c] = __builtin_amdgcn_mfma_f32_16x16x32_bf16(
                            wp[(kk * 4 + c) * 64 + lane], zf, sz[c], 0, 0, 0);
        }
    }

    f32x4 ssum[4] = {(f32x4){0.f,0.f,0.f,0.f}, (f32x4){0.f,0.f,0.f,0.f},
                     (f32x4){0.f,0.f,0.f,0.f}, (f32x4){0.f,0.f,0.f,0.f}};

    for (int s = 0; s < NSTEP; ++s) {
        f32x4 hsum[4];

        // eval 0: H = tanh(sz + VST[s][0]) -> H-buf
        #pragma unroll
        for (int c = 0; c < 4; ++c) {
            f32x4 vst = *(const f32x4*)(smem + L_VST + (s * 4 + 0) * 256 + c * 64 + (hq << 4));
            short4v hc;
            #pragma unroll
            for (int j = 0; j < 4; ++j) {
                float h = ftanh(sz[c][j] + vst[j]);
                hsum[c][j] = h;
                hc[j] = f2bf(h);
            }
            *(short4v*)(smem + L_H + l15 * HP + c * 32 + (hq << 3)) = hc;
        }
        FENCE();

        // evals 1..3: dd = H@G; H' = tanh(sz + c_e*dd + VST[s][e])
        #pragma unroll
        for (int e = 1; e < 4; ++e) {
            const float ce = (e == 3) ? RSTEP : (0.5f * RSTEP);
            const float we = (e == 3) ? 1.f : 2.f;
            short8 hf0 = *(const short8*)(smem + L_H + l15 * HP + (hq << 4));
            short8 hf1 = *(const short8*)(smem + L_H + l15 * HP + 64 + (hq << 4));
            #pragma unroll
            for (int c = 0; c < 4; ++c) {
                f32x4 dd = (f32x4){0.f, 0.f, 0.f, 0.f};
                dd = __builtin_amdgcn_mfma_f32_16x16x32_bf16(gfr[0][c], hf0, dd, 0, 0, 0);
                dd = __builtin_amdgcn_mfma_f32_16x16x32_bf16(gfr[1][c], hf1, dd, 0, 0, 0);
                f32x4 vst = *(const f32x4*)(smem + L_VST + (s * 4 + e) * 256 + c * 64 + (hq << 4));
                short4v hc;
                #pragma unroll
                for (int j = 0; j < 4; ++j) {
                    float h = ftanh(sz[c][j] + ce * dd[j] + vst[j]);
                    hsum[c][j] += we * h;
                    if (e < 3) {
                        hc[j] = f2bf(h);
                    } else {
                        ssum[c][j] += hsum[c][j] * (RSTEP / 6.f);
                        hc[j] = (s < NSTEP - 1) ? f2bf(hsum[c][j] * (RSTEP / 6.f))
                                                : f2bf(ssum[c][j]);
                    }
                }
                *(short4v*)(smem + L_H + l15 * HP + c * 32 + (hq << 3)) = hc;
            }
            FENCE();
        }

        // sz update: sz += Hb@G + h*u  (Hb B-frags from H-buf; skip last step)
        if (s < NSTEP - 1) {
            short8 hb0 = *(const short8*)(smem + L_H + l15 * HP + (hq << 4));
            short8 hb1 = *(const short8*)(smem + L_H + l15 * HP + 64 + (hq << 4));
            #pragma unroll
            for (int c = 0; c < 4; ++c) {
                f32x4 d = (f32x4){0.f, 0.f, 0.f, 0.f};
                d = __builtin_amdgcn_mfma_f32_16x16x32_bf16(gfr[0][c], hb0, d, 0, 0, 0);
                d = __builtin_amdgcn_mfma_f32_16x16x32_bf16(gfr[1][c], hb1, d, 0, 0, 0);
                f32x4 hu4 = *(const f32x4*)(smem + L_HU + c * 64 + (hq << 4));
                #pragma unroll
                for (int j = 0; j < 4; ++j)
                    sz[c][j] += d[j] + hu4[j];
            }
        }
    }

    // ---- epilogue (once): z_T = x + S @ W2 + b2, all 64 col-tiles ----
    // H-buf holds bf16(S) (written at eval3 of the last step; FENCE'd).
    {
        short8 sb0 = *(const short8*)(smem + L_H + l15 * HP + (hq << 4));
        short8 sb1 = *(const short8*)(smem + L_H + l15 * HP + 64 + (hq << 4));
        const short8* w2p8 = (const short8*)W2P;
        float* orow = OUT + (row0 + l15) * DM;
        #pragma unroll 4
        for (int ct = 0; ct < 64; ++ct) {
            short8 wa = w2p8[ct * 64 + lane];
            short8 wb = w2p8[(64 + ct) * 64 + lane];
            f32x4 p = (f32x4){0.f, 0.f, 0.f, 0.f};
            p = __builtin_amdgcn_mfma_f32_16x16x32_bf16(wa, sb0, p, 0, 0, 0);
            p = __builtin_amdgcn_mfma_f32_16x16x32_bf16(wb, sb1, p, 0, 0, 0);
            int col = ct * 16 + (hq << 2);
            f32x4 xv  = *(const f32x4*)(xrow + col);     // L3-resident re-read
            f32x4 b2v = *(const f32x4*)(b2 + col);       // L2-hot broadcast
            f32x4 nv;
            #pragma unroll
            for (int j = 0; j < 4; ++j)
                nv[j] = xv[j] + p[j] + b2v[j];           // sum_s h*b2 = b2
            *(f32x4*)(orow + col) = nv;
        }
    }
}

extern "C" void kernel_launch(void* const* d_in, const int* in_sizes, int n_in,
                              void* d_out, int out_size, void* d_ws, size_t ws_size,
                              hipStream_t stream) {
    (void)in_sizes; (void)n_in; (void)out_size; (void)ws_size;
    const float* X  = (const float*)d_in[0];
    const float* W1 = (const float*)d_in[1];
    const float* b1 = (const float*)d_in[2];
    const float* W2 = (const float*)d_in[3];
    const float* b2 = (const float*)d_in[4];
    float* OUT = (float*)d_out;
    short* W1P = (short*)((char*)d_ws + WS_W1P);
    short* W2P = (short*)((char*)d_ws + WS_W2P);
    short* GP  = (short*)((char*)d_ws + WS_GP);
    float* U   = (float*)((char*)d_ws + WS_U);
    float* VST = (float*)((char*)d_ws + WS_VST);
    float* HU  = (float*)((char*)d_ws + WS_HU);

    k_prep<<<321, 256, 0, stream>>>(W1, W2, b1, b2, W1P, W2P, GP, U, VST, HU);
    k_ode<<<1024, 64, LDS_TOTAL, stream>>>(X, b2, W1P, W2P, GP, VST, HU, OUT);
}

// Round 14
// 72.138 us; speedup vs baseline: 1.1681x; 1.1681x over previous
//
#include <hip/hip_runtime.h>
#include <hip/hip_bf16.h>

#define DM 1024
#define HID 64
#define NSTEP 6
#define RSTEP (1.0f/6.0f)

using short8  = __attribute__((ext_vector_type(8))) short;
using short4v = __attribute__((ext_vector_type(4))) short;
using f32x4   = __attribute__((ext_vector_type(4))) float;

// workspace byte offsets
#define WS_W1P 0          // 1024x64 bf16 packed A-frags (131072 B)
#define WS_W2P 131072     // 64x1024 bf16 packed A-frags (131072 B)
#define WS_GP  262144     // 64x64 bf16 packed A-frags (8192 B)
#define WS_U   270336     // 64 f32  (u = b2 @ W1k)
#define WS_VST 270592     // 24x64 f32 affine stage consts (6144 B)
#define WS_HU  276736     // 64 f32  (h*u) (256 B)

// LDS per block (1 wave): H-buf + VST + HU + b2 = 12800 B
#define L_H   0           // H [16][72] bf16, pitch 144 (2304)
#define L_VST 2304        // VST staged (6144)
#define L_HU  8448        // h*u staged (256)
#define L_B2  8704        // b2 staged f32[1024] (4096)
#define LDS_TOTAL 12800
#define HP 144

// Intra-wave LDS ordering only: the DS pipe services a wave's LDS ops in
// order; this stops the compiler migrating ds ops across phases. The
// whole kernel has ZERO s_barrier (one wave per block). lgkm-only: vmcnt
// stays untouched so global loads ride across fences.
#define FENCE() asm volatile("s_waitcnt lgkmcnt(0)" ::: "memory")

__device__ __forceinline__ short f2bf(float f) {   // RNE via HW cvt
    __hip_bfloat16 h = __float2bfloat16(f);
    short s;
    __builtin_memcpy(&s, &h, 2);
    return s;
}
__device__ __forceinline__ float ftanh(float x) {
    x = fminf(fmaxf(x, -10.f), 10.f);
    float e = __expf(2.f * x);
    return __fdividef(e - 1.f, e + 1.f);
}

// ---------------- prep: pack weights + precompute stage tables ----------------
// Re-gridded to 129 fat blocks (all 256 threads active in pack branches).
__global__ void k_prep(const float* __restrict__ W1, const float* __restrict__ W2,
                       const float* __restrict__ b1, const float* __restrict__ b2,
                       short* __restrict__ W1P, short* __restrict__ W2P,
                       short* __restrict__ GP, float* __restrict__ U,
                       float* __restrict__ VST, float* __restrict__ HU) {
    __shared__ float red[4][64];
    int b = blockIdx.x;
    int t = threadIdx.x;           // 256 threads
    int l = t & 63, q4 = t >> 6;
    if (b < 32) {                  // W1P: kk = b, c = q4
        int kk = b, c = q4;
        int col = c * 16 + (l & 15);
        int kb = kk * 32 + ((l >> 4) << 3);
        short8 v;
        #pragma unroll
        for (int i = 0; i < 8; ++i) v[i] = f2bf(W1[(kb + i) * HID + col]);
        *(short8*)(W1P + (((kk * 4 + c) * 64) + l) * 8) = v;
    } else if (b < 64) {           // W2P: unit = (b-32)*4 + q4
        int unit = (b - 32) * 4 + q4;
        int kk2 = unit >> 6, ct = unit & 63;
        int col = ct * 16 + (l & 15);
        int kb = kk2 * 32 + ((l >> 4) << 3);
        short8 v;
        #pragma unroll
        for (int i = 0; i < 8; ++i) v[i] = f2bf(W2[(kb + i) * DM + col]);
        *(short8*)(W2P + (((kk2 * 64 + ct) * 64) + l) * 8) = v;
    } else if (b < 128) {          // G[j][i] = sum_d W2[j][d]*W1[d][i]; j = b-64
        int j = b - 64;
        float acc = 0.f;
        #pragma unroll 8
        for (int d = q4 * 256; d < q4 * 256 + 256; ++d)
            acc += W2[j * DM + d] * W1[d * HID + l];
        red[q4][l] = acc;
        __syncthreads();
        if (t < 64) {
            float a = red[0][l] + red[1][l] + red[2][l] + red[3][l];
            int kk = j >> 5, lk = (j >> 3) & 3, ii = j & 7, c = l >> 4, lo = l & 15;
            GP[(((kk * 4 + c) * 64) + lk * 16 + lo) * 8 + ii] = f2bf(a);
        }
    } else {                       // u = b2@W1k, HU = h*u, VST table
        float acc = 0.f;
        #pragma unroll 8
        for (int d = q4 * 256; d < q4 * 256 + 256; ++d)
            acc += b2[d] * W1[d * HID + l];
        red[q4][l] = acc;
        __syncthreads();
        if (t < 64) {
            float uu = red[0][l] + red[1][l] + red[2][l] + red[3][l];
            U[l] = uu;
            HU[l] = RSTEP * uu;
            float b1l = b1[l];
            float wtl = W1[DM * HID + l];        // time row of W1
            #pragma unroll
            for (int s6 = 0; s6 < 6; ++s6) {
                float ts = RSTEP * (float)s6;
                float tm = ts + 0.5f * RSTEP;
                float vmid = b1l + tm * wtl + 0.5f * RSTEP * uu;
                VST[(s6 * 4 + 0) * 64 + l] = b1l + ts * wtl;
                VST[(s6 * 4 + 1) * 64 + l] = vmid;
                VST[(s6 * 4 + 2) * 64 + l] = vmid;
                VST[(s6 * 4 + 3) * 64 + l] = b1l + (ts + RSTEP) * wtl + RSTEP * uu;
            }
        }
    }
}

// epilogue ping-pong macros (named buffers — rule-#20-safe, no arrays)
#define EPL(W0,W1,W2,W3,X0,X1,P) \
    W0 = w2p8[(P) * 64 + lane];        W1 = w2p8[((P) + 64) * 64 + lane]; \
    W2 = w2p8[((P) + 1) * 64 + lane];  W3 = w2p8[((P) + 65) * 64 + lane]; \
    X0 = *(const f32x4*)(xrow + (P) * 16 + (hq << 2)); \
    X1 = *(const f32x4*)(xrow + ((P) + 1) * 16 + (hq << 2));

#define EPC(W0,W1,W2,W3,X0,X1,P) { \
    f32x4 p0 = (f32x4){0.f,0.f,0.f,0.f}, p1 = (f32x4){0.f,0.f,0.f,0.f}; \
    p0 = __builtin_amdgcn_mfma_f32_16x16x32_bf16(W0, sb0, p0, 0, 0, 0); \
    p0 = __builtin_amdgcn_mfma_f32_16x16x32_bf16(W1, sb1, p0, 0, 0, 0); \
    p1 = __builtin_amdgcn_mfma_f32_16x16x32_bf16(W2, sb0, p1, 0, 0, 0); \
    p1 = __builtin_amdgcn_mfma_f32_16x16x32_bf16(W3, sb1, p1, 0, 0, 0); \
    f32x4 b0v = *(const f32x4*)(smem + L_B2 + ((P) * 16 + (hq << 2)) * 4); \
    f32x4 b1v = *(const f32x4*)(smem + L_B2 + (((P) + 1) * 16 + (hq << 2)) * 4); \
    f32x4 n0, n1; \
    for (int j = 0; j < 4; ++j) { n0[j] = X0[j] + p0[j] + b0v[j]; \
                                  n1[j] = X1[j] + p1[j] + b1v[j]; } \
    *(f32x4*)(orow + (P) * 16 + (hq << 2)) = n0; \
    *(f32x4*)(orow + ((P) + 1) * 16 + (hq << 2)) = n1; }

// ---------------- fused RK4 neural-ODE kernel (wave-local, deep-batched) -----
// R13 structure (one wave = one 16-row group, 0 barriers, incremental sz,
// deferred-z epilogue) with the MEMORY PHASES re-engineered:
//  - prologue: 4 batches x 8 kk, each issuing a 16-deep f32x4 X burst
//    before any cvt/MFMA (R13's unroll-4 held only ~8 loads in flight ->
//    latency-limited ~1.9 TB/s; R12==R13==73us showed these phases bound).
//  - epilogue: explicit 2-ct ping-pong (W2P x4 + x x2 loads one batch
//    ahead, named buffers); b2 pre-staged in LDS at kernel start.
// Step loop verbatim R13. ALLOCATION: amdgpu_waves_per_eu(2,4) (13-round
// ledger). Peak live-set ~100-115 regs.
__global__ __launch_bounds__(64) __attribute__((amdgpu_waves_per_eu(2, 4)))
void k_ode(
        const float* __restrict__ X, const float* __restrict__ b2,
        const short* __restrict__ W1P, const short* __restrict__ W2P,
        const short* __restrict__ GP, const float* __restrict__ VST,
        const float* __restrict__ HU, float* __restrict__ OUT) {
    extern __shared__ char smem[];
    const int lane = threadIdx.x & 63;
    const int hq = lane >> 4;
    const int l15 = lane & 15;
    const size_t row0 = (size_t)blockIdx.x * 16;
    const float* xrow = X + (row0 + l15) * DM;

    // b2 -> LDS (tiny global burst first; consumed only in the epilogue)
    #pragma unroll
    for (int i = 0; i < 4; ++i)
        *(f32x4*)(smem + L_B2 + lane * 64 + i * 16) =
            *(const f32x4*)(b2 + lane * 16 + i * 4);

    // ---- prologue GEMM1: sz[c] = x @ W1k; 16-deep X load bursts ----
    f32x4 sz[4] = {(f32x4){0.f,0.f,0.f,0.f}, (f32x4){0.f,0.f,0.f,0.f},
                   (f32x4){0.f,0.f,0.f,0.f}, (f32x4){0.f,0.f,0.f,0.f}};
    {
        const short8* wp = (const short8*)W1P;
        #pragma unroll
        for (int B = 0; B < 4; ++B) {
            f32x4 lo[8], hi[8];                  // 64 transient VGPRs: the burst
            #pragma unroll
            for (int i = 0; i < 8; ++i) {
                const float* xp = xrow + ((B * 8 + i) << 5) + (hq << 3);
                lo[i] = *(const f32x4*)(xp);
                hi[i] = *(const f32x4*)(xp + 4);
            }
            #pragma unroll
            for (int i = 0; i < 8; ++i) {
                int kk = B * 8 + i;
                short8 zf;
                #pragma unroll
                for (int j = 0; j < 4; ++j) { zf[j] = f2bf(lo[i][j]); zf[4 + j] = f2bf(hi[i][j]); }
                #pragma unroll
                for (int c = 0; c < 4; ++c)
                    sz[c] = __builtin_amdgcn_mfma_f32_16x16x32_bf16(
                                wp[(kk * 4 + c) * 64 + lane], zf, sz[c], 0, 0, 0);
            }
        }
    }

    // VST + HU -> LDS; pinned G A-frags (after the X burst on purpose)
    #pragma unroll
    for (int i = 0; i < 6; ++i)
        *(f32x4*)(smem + L_VST + i * 1024 + lane * 16) =
            *(const f32x4*)(VST + i * 256 + lane * 4);
    if (lane < 16)
        *(f32x4*)(smem + L_HU + lane * 16) = *(const f32x4*)(HU + lane * 4);
    short8 gfr[2][4];
    #pragma unroll
    for (int k2 = 0; k2 < 2; ++k2)
        #pragma unroll
        for (int c = 0; c < 4; ++c)
            gfr[k2][c] = *(const short8*)(GP + ((k2 * 4 + c) * 64 + lane) * 8);
    FENCE();

    f32x4 ssum[4] = {(f32x4){0.f,0.f,0.f,0.f}, (f32x4){0.f,0.f,0.f,0.f},
                     (f32x4){0.f,0.f,0.f,0.f}, (f32x4){0.f,0.f,0.f,0.f}};

    for (int s = 0; s < NSTEP; ++s) {
        f32x4 hsum[4];

        // eval 0: H = tanh(sz + VST[s][0]) -> H-buf
        #pragma unroll
        for (int c = 0; c < 4; ++c) {
            f32x4 vst = *(const f32x4*)(smem + L_VST + (s * 4 + 0) * 256 + c * 64 + (hq << 4));
            short4v hc;
            #pragma unroll
            for (int j = 0; j < 4; ++j) {
                float h = ftanh(sz[c][j] + vst[j]);
                hsum[c][j] = h;
                hc[j] = f2bf(h);
            }
            *(short4v*)(smem + L_H + l15 * HP + c * 32 + (hq << 3)) = hc;
        }
        FENCE();

        // evals 1..3: dd = H@G; H' = tanh(sz + c_e*dd + VST[s][e])
        #pragma unroll
        for (int e = 1; e < 4; ++e) {
            const float ce = (e == 3) ? RSTEP : (0.5f * RSTEP);
            const float we = (e == 3) ? 1.f : 2.f;
            short8 hf0 = *(const short8*)(smem + L_H + l15 * HP + (hq << 4));
            short8 hf1 = *(const short8*)(smem + L_H + l15 * HP + 64 + (hq << 4));
            #pragma unroll
            for (int c = 0; c < 4; ++c) {
                f32x4 dd = (f32x4){0.f, 0.f, 0.f, 0.f};
                dd = __builtin_amdgcn_mfma_f32_16x16x32_bf16(gfr[0][c], hf0, dd, 0, 0, 0);
                dd = __builtin_amdgcn_mfma_f32_16x16x32_bf16(gfr[1][c], hf1, dd, 0, 0, 0);
                f32x4 vst = *(const f32x4*)(smem + L_VST + (s * 4 + e) * 256 + c * 64 + (hq << 4));
                short4v hc;
                #pragma unroll
                for (int j = 0; j < 4; ++j) {
                    float h = ftanh(sz[c][j] + ce * dd[j] + vst[j]);
                    hsum[c][j] += we * h;
                    if (e < 3) {
                        hc[j] = f2bf(h);
                    } else {
                        ssum[c][j] += hsum[c][j] * (RSTEP / 6.f);
                        hc[j] = (s < NSTEP - 1) ? f2bf(hsum[c][j] * (RSTEP / 6.f))
                                                : f2bf(ssum[c][j]);
                    }
                }
                *(short4v*)(smem + L_H + l15 * HP + c * 32 + (hq << 3)) = hc;
            }
            FENCE();
        }

        // sz update: sz += Hb@G + h*u  (skip on last step)
        if (s < NSTEP - 1) {
            short8 hb0 = *(const short8*)(smem + L_H + l15 * HP + (hq << 4));
            short8 hb1 = *(const short8*)(smem + L_H + l15 * HP + 64 + (hq << 4));
            #pragma unroll
            for (int c = 0; c < 4; ++c) {
                f32x4 d = (f32x4){0.f, 0.f, 0.f, 0.f};
                d = __builtin_amdgcn_mfma_f32_16x16x32_bf16(gfr[0][c], hb0, d, 0, 0, 0);
                d = __builtin_amdgcn_mfma_f32_16x16x32_bf16(gfr[1][c], hb1, d, 0, 0, 0);
                f32x4 hu4 = *(const f32x4*)(smem + L_HU + c * 64 + (hq << 4));
                #pragma unroll
                for (int j = 0; j < 4; ++j)
                    sz[c][j] += d[j] + hu4[j];
            }
        }
    }

    // ---- epilogue: z_T = x + S@W2 + b2; ping-pong ct pairs, 1 batch ahead
    {
        short8 sb0 = *(const short8*)(smem + L_H + l15 * HP + (hq << 4));
        short8 sb1 = *(const short8*)(smem + L_H + l15 * HP + 64 + (hq << 4));
        const short8* w2p8 = (const short8*)W2P;
        float* orow = OUT + (row0 + l15) * DM;

        short8 wA0, wA1, wA2, wA3; f32x4 xA0, xA1;
        short8 wB0, wB1, wB2, wB3; f32x4 xB0, xB1;
        EPL(wA0, wA1, wA2, wA3, xA0, xA1, 0)
        #pragma unroll
        for (int p = 0; p < 64; p += 4) {
            EPL(wB0, wB1, wB2, wB3, xB0, xB1, p + 2)
            EPC(wA0, wA1, wA2, wA3, xA0, xA1, p)
            if (p + 4 < 64) { EPL(wA0, wA1, wA2, wA3, xA0, xA1, p + 4) }
            EPC(wB0, wB1, wB2, wB3, xB0, xB1, p + 2)
        }
    }
}

extern "C" void kernel_launch(void* const* d_in, const int* in_sizes, int n_in,
                              void* d_out, int out_size, void* d_ws, size_t ws_size,
                              hipStream_t stream) {
    (void)in_sizes; (void)n_in; (void)out_size; (void)ws_size;
    const float* X  = (const float*)d_in[0];
    const float* W1 = (const float*)d_in[1];
    const float* b1 = (const float*)d_in[2];
    const float* W2 = (const float*)d_in[3];
    const float* b2 = (const float*)d_in[4];
    float* OUT = (float*)d_out;
    short* W1P = (short*)((char*)d_ws + WS_W1P);
    short* W2P = (short*)((char*)d_ws + WS_W2P);
    short* GP  = (short*)((char*)d_ws + WS_GP);
    float* U   = (float*)((char*)d_ws + WS_U);
    float* VST = (float*)((char*)d_ws + WS_VST);
    float* HU  = (float*)((char*)d_ws + WS_HU);

    k_prep<<<129, 256, 0, stream>>>(W1, W2, b1, b2, W1P, W2P, GP, U, VST, HU);
    k_ode<<<1024, 64, LDS_TOTAL, stream>>>(X, b2, W1P, W2P, GP, VST, HU, OUT);
}